// Round 2
// baseline (2104.336 us; speedup 1.0000x reference)
//
#include <hip/hip_runtime.h>

#define NN 50000
#define EE 150000
#define BN_EPS 1e-5f
#define SLOPE 0.01f

// zero the BN stats accumulators (ws is re-poisoned before every call)
__global__ __launch_bounds__(256) void k_zero_stats(float* __restrict__ stats) {
    int i = threadIdx.x;
    if (i < 3 * 64) stats[i] = 0.0f;
}

// hpre[v] = bias + h[v] @ root
__global__ __launch_bounds__(256) void k_pre(const float* __restrict__ h,
                                             const float* __restrict__ root,
                                             const float* __restrict__ bias,
                                             float* __restrict__ hpre) {
    int v = blockIdx.x * blockDim.x + threadIdx.x;
    if (v >= NN) return;
    float hv[32];
    const float4* hp = (const float4*)(h + v * 32);
#pragma unroll
    for (int q = 0; q < 8; ++q) {
        float4 t = hp[q];
        hv[4 * q] = t.x; hv[4 * q + 1] = t.y; hv[4 * q + 2] = t.z; hv[4 * q + 3] = t.w;
    }
    float acc[32];
#pragma unroll
    for (int o = 0; o < 32; ++o) acc[o] = bias[o];
#pragma unroll
    for (int i = 0; i < 32; ++i) {
        float z = hv[i];
#pragma unroll
        for (int o = 0; o < 32; ++o) acc[o] = fmaf(z, root[i * 32 + o], acc[o]);
    }
    float4* op = (float4*)(hpre + v * 32);
#pragma unroll
    for (int q = 0; q < 8; ++q)
        op[q] = make_float4(acc[4 * q], acc[4 * q + 1], acc[4 * q + 2], acc[4 * q + 3]);
}

// per edge: m = h[src] @ (sum_k relu(ea@W1+b1)_k * W2[k] + b2); atomically add to hpre[dst]
__global__ __launch_bounds__(256) void k_msg(
    const float* __restrict__ h, const int* __restrict__ ei,
    const float* __restrict__ ea, const float* __restrict__ W1,
    const float* __restrict__ b1, const float* __restrict__ W2,
    const float* __restrict__ b2, float* __restrict__ hpre)
{
    int e = blockIdx.x * blockDim.x + threadIdx.x;
    if (e >= EE) return;
    int s = ei[e];
    int d = ei[EE + e];
    float2 a = ((const float2*)ea)[e];

    float hv[32];
    const float4* hp = (const float4*)(h + s * 32);
#pragma unroll
    for (int q = 0; q < 8; ++q) {
        float4 t = hp[q];
        hv[4 * q] = t.x; hv[4 * q + 1] = t.y; hv[4 * q + 2] = t.z; hv[4 * q + 3] = t.w;
    }

    float acc[32];
#pragma unroll
    for (int o = 0; o < 32; ++o) acc[o] = 0.0f;

    // b2 part: acc[o] += sum_i hv[i] * b2[i*32+o]
#pragma unroll
    for (int i = 0; i < 32; ++i) {
        float z = hv[i];
#pragma unroll
        for (int o = 0; o < 32; ++o) acc[o] = fmaf(z, b2[i * 32 + o], acc[o]);
    }

    for (int k = 0; k < 10; ++k) {
        float ekk = fmaf(a.x, W1[k], fmaf(a.y, W1[10 + k], b1[k]));
        ekk = fmaxf(ekk, 0.0f);
        const float* w2k = W2 + k * 1024;
#pragma unroll
        for (int i = 0; i < 32; ++i) {
            float z = ekk * hv[i];
#pragma unroll
            for (int o = 0; o < 32; ++o) acc[o] = fmaf(z, w2k[i * 32 + o], acc[o]);
        }
    }

    float* dp = hpre + d * 32;
#pragma unroll
    for (int o = 0; o < 32; ++o) unsafeAtomicAdd(&dp[o], acc[o]);
}

// BN batch moments over completed hpre
__global__ __launch_bounds__(256) void k_stats(const float* __restrict__ hpre,
                                               float* __restrict__ stats) {
    int v = blockIdx.x * blockDim.x + threadIdx.x;
    bool act = (v < NN);
    float acc[32];
    if (act) {
        const float4* hp = (const float4*)(hpre + v * 32);
#pragma unroll
        for (int q = 0; q < 8; ++q) {
            float4 t = hp[q];
            acc[4 * q] = t.x; acc[4 * q + 1] = t.y; acc[4 * q + 2] = t.z; acc[4 * q + 3] = t.w;
        }
    } else {
#pragma unroll
        for (int o = 0; o < 32; ++o) acc[o] = 0.0f;
    }
#pragma unroll
    for (int o = 0; o < 32; ++o) {
        float s = acc[o];
        float q = s * s;
#pragma unroll
        for (int dd = 32; dd > 0; dd >>= 1) {
            s += __shfl_xor(s, dd);
            q += __shfl_xor(q, dd);
        }
        if ((threadIdx.x & 63) == 0) {
            unsafeAtomicAdd(&stats[o], s);
            unsafeAtomicAdd(&stats[32 + o], q);
        }
    }
}

__global__ void k_finalize(const float* __restrict__ stats, const float* __restrict__ gamma,
                           const float* __restrict__ beta, float* __restrict__ scsh) {
    int o = threadIdx.x;
    if (o < 32) {
        double mu = (double)stats[o] / NN;
        double var = (double)stats[32 + o] / NN - mu * mu;
        float rstd = (float)(1.0 / sqrt(var + (double)BN_EPS));
        float sc = gamma[o] * rstd;
        scsh[o] = sc;
        scsh[32 + o] = beta[o] - (float)mu * sc;
    }
}

__global__ __launch_bounds__(256) void k_norm(float* __restrict__ h, const float* __restrict__ scsh) {
    int i = blockIdx.x * blockDim.x + threadIdx.x;
    if (i < NN * 8) {
        float4 v = ((float4*)h)[i];
        int c0 = (i * 4) & 31;
        v.x = fmaf(v.x, scsh[c0 + 0], scsh[32 + c0 + 0]); v.x = v.x > 0.f ? v.x : SLOPE * v.x;
        v.y = fmaf(v.y, scsh[c0 + 1], scsh[32 + c0 + 1]); v.y = v.y > 0.f ? v.y : SLOPE * v.y;
        v.z = fmaf(v.z, scsh[c0 + 2], scsh[32 + c0 + 2]); v.z = v.z > 0.f ? v.z : SLOPE * v.z;
        v.w = fmaf(v.w, scsh[c0 + 3], scsh[32 + c0 + 3]); v.w = v.w > 0.f ? v.w : SLOPE * v.w;
        ((float4*)h)[i] = v;
    }
}

__global__ __launch_bounds__(256) void k_logits(const float* __restrict__ h,
                                                const float* __restrict__ fcW,
                                                const float* __restrict__ fcb,
                                                float* __restrict__ out) {
    int v = blockIdx.x * blockDim.x + threadIdx.x;
    if (v >= NN) return;
    float hv[32];
    const float4* hp = (const float4*)(h + v * 32);
#pragma unroll
    for (int q = 0; q < 8; ++q) {
        float4 t = hp[q];
        hv[4 * q] = t.x; hv[4 * q + 1] = t.y; hv[4 * q + 2] = t.z; hv[4 * q + 3] = t.w;
    }
    float lg[13];
#pragma unroll
    for (int c = 0; c < 13; ++c) lg[c] = fcb[c];
#pragma unroll
    for (int i = 0; i < 32; ++i) {
        float z = hv[i];
#pragma unroll
        for (int c = 0; c < 13; ++c) lg[c] = fmaf(z, fcW[i * 13 + c], lg[c]);
    }
    float mx = lg[0];
#pragma unroll
    for (int c = 1; c < 13; ++c) mx = fmaxf(mx, lg[c]);
    float sum = 0.0f;
#pragma unroll
    for (int c = 0; c < 13; ++c) sum += expf(lg[c] - mx);
    float lse = mx + logf(sum);
#pragma unroll
    for (int c = 0; c < 13; ++c) out[v * 13 + c] = lg[c] - lse;
}

// ---------------- launch ----------------
extern "C" void kernel_launch(void* const* d_in, const int* in_sizes, int n_in,
                              void* d_out, int out_size, void* d_ws, size_t ws_size,
                              hipStream_t stream) {
    const float* x     = (const float*)d_in[0];
    const int*   ei    = (const int*)  d_in[1];
    const float* ea    = (const float*)d_in[2];
    const float* netW1 = (const float*)d_in[3];
    const float* netb1 = (const float*)d_in[4];
    const float* netW2 = (const float*)d_in[5];
    const float* netb2 = (const float*)d_in[6];
    const float* root  = (const float*)d_in[7];
    const float* cbias = (const float*)d_in[8];
    const float* gamma = (const float*)d_in[9];
    const float* beta  = (const float*)d_in[10];
    const float* fcW   = (const float*)d_in[11];
    const float* fcb   = (const float*)d_in[12];
    float* out = (float*)d_out;

    char* w = (char*)d_ws;
    float* hA    = (float*)(w);             // 6,400,000 B
    float* hB    = (float*)(w + 6400000);   // 6,400,000 B
    float* stats = (float*)(w + 12800000);  // 3*64*4 B
    float* scsh  = (float*)(w + 12801024);  // 3*64*4 B

    k_zero_stats<<<1, 256, 0, stream>>>(stats);

    const float* hcur = x;
    float* bufs[2] = { hA, hB };
    for (int i = 0; i < 3; ++i) {
        float* hnext = bufs[i & 1];
        k_pre<<<(NN + 255) / 256, 256, 0, stream>>>(hcur, root + i * 1024, cbias + i * 32, hnext);
        k_msg<<<(EE + 255) / 256, 256, 0, stream>>>(
            hcur, ei, ea, netW1 + i * 20, netb1 + i * 10,
            netW2 + i * 10240, netb2 + i * 1024, hnext);
        k_stats<<<(NN + 255) / 256, 256, 0, stream>>>(hnext, stats + i * 64);
        k_finalize<<<1, 64, 0, stream>>>(stats + i * 64, gamma + i * 32, beta + i * 32, scsh + i * 64);
        k_norm<<<(NN * 8 + 255) / 256, 256, 0, stream>>>(hnext, scsh + i * 64);
        hcur = hnext;
    }
    k_logits<<<(NN + 255) / 256, 256, 0, stream>>>(hcur, fcW, fcb, out);
}

// Round 3
// 620.766 us; speedup vs baseline: 3.3899x; 3.3899x over previous
//
#include <hip/hip_runtime.h>

#define NN 50000
#define EE 150000
#define BN_EPS 1e-5f
#define SLOPE 0.01f

// ---------------- CSR build ----------------
__global__ __launch_bounds__(256) void k_zero(int* __restrict__ cnt, float* __restrict__ stats) {
    int i = blockIdx.x * blockDim.x + threadIdx.x;
    if (i < NN + 1) cnt[i] = 0;
    if (i < 3 * 64) stats[i] = 0.0f;
}

__global__ __launch_bounds__(256) void k_count(const int* __restrict__ ei, int* __restrict__ cnt) {
    int e = blockIdx.x * blockDim.x + threadIdx.x;
    if (e < EE) atomicAdd(&cnt[ei[EE + e]], 1);
}

// single block: exclusive scan of cnt[0..NN] -> rowptr, cursor
__global__ __launch_bounds__(1024) void k_scan(const int* __restrict__ cnt,
                                               int* __restrict__ rowptr,
                                               int* __restrict__ cursor) {
    __shared__ int part[1024];
    const int T = 1024;
    const int CH = (NN + 1 + T - 1) / T;
    int t = threadIdx.x;
    int base = t * CH;
    int s = 0;
    for (int j = 0; j < CH; ++j) {
        int idx = base + j;
        if (idx < NN + 1) s += cnt[idx];
    }
    part[t] = s;
    __syncthreads();
    for (int off = 1; off < T; off <<= 1) {
        int val = (t >= off) ? part[t - off] : 0;
        __syncthreads();
        part[t] += val;
        __syncthreads();
    }
    int run = (t == 0) ? 0 : part[t - 1];
    for (int j = 0; j < CH; ++j) {
        int idx = base + j;
        if (idx < NN + 1) {
            int c = cnt[idx];
            rowptr[idx] = run;
            cursor[idx] = run;
            run += c;
        }
    }
}

// perm[e] = CSR slot for edge e (grouped by dst)
__global__ __launch_bounds__(256) void k_fill(const int* __restrict__ ei,
                                              int* __restrict__ cursor,
                                              int* __restrict__ perm) {
    int e = blockIdx.x * blockDim.x + threadIdx.x;
    if (e < EE) perm[e] = atomicAdd(&cursor[ei[EE + e]], 1);
}

// ---------------- per-layer kernels ----------------
// message per edge, written to CSR-permuted slot; h read through fused BN+leakyrelu
__global__ __launch_bounds__(256) void k_msg(
    const float* __restrict__ h, const int* __restrict__ ei,
    const float* __restrict__ ea, const float* __restrict__ W1,
    const float* __restrict__ b1, const float* __restrict__ W2,
    const float* __restrict__ b2, const float* __restrict__ scsh, int flag,
    const int* __restrict__ perm, float* __restrict__ m)
{
    int e = blockIdx.x * blockDim.x + threadIdx.x;
    if (e >= EE) return;
    int s = ei[e];
    float2 a = ((const float2*)ea)[e];

    float ek[11];
#pragma unroll
    for (int k = 0; k < 10; ++k)
        ek[k] = fmaxf(fmaf(a.x, W1[k], fmaf(a.y, W1[10 + k], b1[k])), 0.0f);
    ek[10] = 1.0f;   // b2 treated as 11th basis matrix

    float hv[32];
    const float4* hp = (const float4*)(h + s * 32);
#pragma unroll
    for (int q = 0; q < 8; ++q) {
        float4 t = hp[q];
        hv[4 * q] = t.x; hv[4 * q + 1] = t.y; hv[4 * q + 2] = t.z; hv[4 * q + 3] = t.w;
    }
    if (flag) {
#pragma unroll
        for (int i = 0; i < 32; ++i) {
            float y = fmaf(hv[i], scsh[i], scsh[32 + i]);
            hv[i] = y > 0.f ? y : SLOPE * y;
        }
    }

    float acc[32];
#pragma unroll
    for (int o = 0; o < 32; ++o) acc[o] = 0.0f;

    for (int k = 0; k < 11; ++k) {
        const float* w2k = (k < 10) ? (W2 + k * 1024) : b2;   // wave-uniform select
        float ekk = ek[k];
#pragma unroll
        for (int i = 0; i < 32; ++i) {
            float z = ekk * hv[i];
#pragma unroll
            for (int o = 0; o < 32; ++o) acc[o] = fmaf(z, w2k[i * 32 + o], acc[o]);
        }
    }

    float4* mp = (float4*)(m + (size_t)perm[e] * 32);
#pragma unroll
    for (int q = 0; q < 8; ++q)
        mp[q] = make_float4(acc[4 * q], acc[4 * q + 1], acc[4 * q + 2], acc[4 * q + 3]);
}

// 8 threads/node: hpre[v] = bias + norm(h[v])@root + sum of contiguous CSR message rows
__global__ __launch_bounds__(256) void k_agg(
    const float* __restrict__ h, const float* __restrict__ m,
    const int* __restrict__ rowptr,
    const float* __restrict__ root, const float* __restrict__ bias,
    const float* __restrict__ scsh, int flag,
    float* __restrict__ hpre, float* __restrict__ stats)
{
    int v = blockIdx.x * 32 + (threadIdx.x >> 3);
    int cg = threadIdx.x & 7;
    float4 acc = make_float4(0.f, 0.f, 0.f, 0.f);

    if (v < NN) {
        float hn[32];
        const float4* hp = (const float4*)(h + v * 32);
#pragma unroll
        for (int q = 0; q < 8; ++q) {
            float4 t = hp[q];
            hn[4 * q] = t.x; hn[4 * q + 1] = t.y; hn[4 * q + 2] = t.z; hn[4 * q + 3] = t.w;
        }
        if (flag) {
#pragma unroll
            for (int i = 0; i < 32; ++i) {
                float y = fmaf(hn[i], scsh[i], scsh[32 + i]);
                hn[i] = y > 0.f ? y : SLOPE * y;
            }
        }
        acc = ((const float4*)bias)[cg];
#pragma unroll
        for (int i = 0; i < 32; ++i) {
            float4 r = ((const float4*)(root + i * 32))[cg];
            acc.x = fmaf(hn[i], r.x, acc.x);
            acc.y = fmaf(hn[i], r.y, acc.y);
            acc.z = fmaf(hn[i], r.z, acc.z);
            acc.w = fmaf(hn[i], r.w, acc.w);
        }
        int p0 = rowptr[v], p1 = rowptr[v + 1];
        for (int p = p0; p < p1; ++p) {
            float4 t = ((const float4*)(m + (size_t)p * 32))[cg];
            acc.x += t.x; acc.y += t.y; acc.z += t.z; acc.w += t.w;
        }
        ((float4*)(hpre + v * 32))[cg] = acc;
    }

    // BN stats: butterfly over the 8 nodes in each wave, LDS reduce over waves, 64 atomics/block
    float ss[8] = { acc.x, acc.y, acc.z, acc.w,
                    acc.x * acc.x, acc.y * acc.y, acc.z * acc.z, acc.w * acc.w };
#pragma unroll
    for (int d = 8; d < 64; d <<= 1) {
#pragma unroll
        for (int j = 0; j < 8; ++j) ss[j] += __shfl_xor(ss[j], d);
    }
    __shared__ float ls[2][4][8][4];
    int wave = threadIdx.x >> 6, lane = threadIdx.x & 63;
    if (lane < 8) {
#pragma unroll
        for (int j = 0; j < 4; ++j) {
            ls[0][wave][lane][j] = ss[j];
            ls[1][wave][lane][j] = ss[4 + j];
        }
    }
    __syncthreads();
    if (threadIdx.x < 64) {
        int stat = threadIdx.x >> 5, idx = threadIdx.x & 31;
        int cgg = idx >> 2, ch = idx & 3;
        float val = ls[stat][0][cgg][ch] + ls[stat][1][cgg][ch]
                  + ls[stat][2][cgg][ch] + ls[stat][3][cgg][ch];
        unsafeAtomicAdd(&stats[stat * 32 + idx], val);
    }
}

__global__ void k_finalize(const float* __restrict__ stats, const float* __restrict__ gamma,
                           const float* __restrict__ beta, float* __restrict__ scsh) {
    int o = threadIdx.x;
    if (o < 32) {
        double mu = (double)stats[o] / NN;
        double var = (double)stats[32 + o] / NN - mu * mu;
        float rstd = (float)(1.0 / sqrt(var + (double)BN_EPS));
        float sc = gamma[o] * rstd;
        scsh[o] = sc;
        scsh[32 + o] = beta[o] - (float)mu * sc;
    }
}

// final-layer norm fused here
__global__ __launch_bounds__(256) void k_logits(const float* __restrict__ h,
                                                const float* __restrict__ fcW,
                                                const float* __restrict__ fcb,
                                                const float* __restrict__ scsh,
                                                float* __restrict__ out) {
    int v = blockIdx.x * blockDim.x + threadIdx.x;
    if (v >= NN) return;
    float hv[32];
    const float4* hp = (const float4*)(h + v * 32);
#pragma unroll
    for (int q = 0; q < 8; ++q) {
        float4 t = hp[q];
        hv[4 * q] = t.x; hv[4 * q + 1] = t.y; hv[4 * q + 2] = t.z; hv[4 * q + 3] = t.w;
    }
#pragma unroll
    for (int i = 0; i < 32; ++i) {
        float y = fmaf(hv[i], scsh[i], scsh[32 + i]);
        hv[i] = y > 0.f ? y : SLOPE * y;
    }
    float lg[13];
#pragma unroll
    for (int c = 0; c < 13; ++c) lg[c] = fcb[c];
#pragma unroll
    for (int i = 0; i < 32; ++i) {
        float z = hv[i];
#pragma unroll
        for (int c = 0; c < 13; ++c) lg[c] = fmaf(z, fcW[i * 13 + c], lg[c]);
    }
    float mx = lg[0];
#pragma unroll
    for (int c = 1; c < 13; ++c) mx = fmaxf(mx, lg[c]);
    float sum = 0.0f;
#pragma unroll
    for (int c = 0; c < 13; ++c) sum += expf(lg[c] - mx);
    float lse = mx + logf(sum);
#pragma unroll
    for (int c = 0; c < 13; ++c) out[v * 13 + c] = lg[c] - lse;
}

// ---------------- launch ----------------
extern "C" void kernel_launch(void* const* d_in, const int* in_sizes, int n_in,
                              void* d_out, int out_size, void* d_ws, size_t ws_size,
                              hipStream_t stream) {
    const float* x     = (const float*)d_in[0];
    const int*   ei    = (const int*)  d_in[1];
    const float* ea    = (const float*)d_in[2];
    const float* netW1 = (const float*)d_in[3];
    const float* netb1 = (const float*)d_in[4];
    const float* netW2 = (const float*)d_in[5];
    const float* netb2 = (const float*)d_in[6];
    const float* root  = (const float*)d_in[7];
    const float* cbias = (const float*)d_in[8];
    const float* gamma = (const float*)d_in[9];
    const float* beta  = (const float*)d_in[10];
    const float* fcW   = (const float*)d_in[11];
    const float* fcb   = (const float*)d_in[12];
    float* out = (float*)d_out;

    char* w = (char*)d_ws;
    float* m      = (float*)(w);                 // 19,200,000 B
    float* hA     = (float*)(w + 19200000);      //  6,400,000 B
    float* hB     = (float*)(w + 25600000);      //  6,400,000 B
    int*   rowptr = (int*)  (w + 32000000);      //    200,064 B
    int*   cursor = (int*)  (w + 32200064);      //    200,064 B
    int*   perm   = (int*)  (w + 32400128);      //    600,000 B
    float* stats  = (float*)(w + 33000128);      //        768 B
    float* scsh   = (float*)(w + 33000896);      //        768 B
    int*   cnt    = (int*)w;                     // overlaps m (used only before m is written)

    k_zero <<<(NN + 256) / 256, 256, 0, stream>>>(cnt, stats);
    k_count<<<(EE + 255) / 256, 256, 0, stream>>>(ei, cnt);
    k_scan <<<1, 1024, 0, stream>>>(cnt, rowptr, cursor);
    k_fill <<<(EE + 255) / 256, 256, 0, stream>>>(ei, cursor, perm);

    const float* hcur = x;
    float* bufs[2] = { hA, hB };
    for (int i = 0; i < 3; ++i) {
        float* hnext = bufs[i & 1];
        const float* scprev = scsh + (i - 1) * 64;   // unused when i==0
        k_msg<<<(EE + 255) / 256, 256, 0, stream>>>(
            hcur, ei, ea, netW1 + i * 20, netb1 + i * 10,
            netW2 + i * 10240, netb2 + i * 1024, scprev, i > 0, perm, m);
        k_agg<<<(NN + 31) / 32, 256, 0, stream>>>(
            hcur, m, rowptr, root + i * 1024, cbias + i * 32,
            scprev, i > 0, hnext, stats + i * 64);
        k_finalize<<<1, 64, 0, stream>>>(stats + i * 64, gamma + i * 32, beta + i * 32, scsh + i * 64);
        hcur = hnext;
    }
    k_logits<<<(NN + 255) / 256, 256, 0, stream>>>(hcur, fcW, fcb, scsh + 2 * 64, out);
}

// Round 4
// 513.303 us; speedup vs baseline: 4.0996x; 1.2094x over previous
//
#include <hip/hip_runtime.h>

#define NN 50000
#define EE 150000
#define BN_EPS 1e-5f
#define SLOPE 0.01f
#define SCAN_B 196   // ceil((NN+1)/256)

// ---------------- CSR build ----------------
__global__ __launch_bounds__(256) void k_count(const int* __restrict__ ei, int* __restrict__ cnt) {
    int e = blockIdx.x * blockDim.x + threadIdx.x;
    if (e < EE) atomicAdd(&cnt[ei[EE + e]], 1);
}

// per-block exclusive scan; block sums to bsum
__global__ __launch_bounds__(256) void k_scanA(const int* __restrict__ cnt,
                                               int* __restrict__ rowptr,
                                               int* __restrict__ bsum) {
    __shared__ int buf[256];
    int t = threadIdx.x;
    int idx = blockIdx.x * 256 + t;
    int v = (idx <= NN) ? cnt[idx] : 0;
    buf[t] = v;
    __syncthreads();
    for (int off = 1; off < 256; off <<= 1) {
        int add = (t >= off) ? buf[t - off] : 0;
        __syncthreads();
        buf[t] += add;
        __syncthreads();
    }
    if (idx <= NN) rowptr[idx] = buf[t] - v;          // exclusive within block
    if (t == 255) bsum[blockIdx.x] = buf[255];        // block total
}

// exclusive scan of the block sums (single small block)
__global__ __launch_bounds__(256) void k_scanB(int* __restrict__ bsum) {
    __shared__ int buf[256];
    int t = threadIdx.x;
    int v = (t < SCAN_B) ? bsum[t] : 0;
    buf[t] = v;
    __syncthreads();
    for (int off = 1; off < 256; off <<= 1) {
        int add = (t >= off) ? buf[t - off] : 0;
        __syncthreads();
        buf[t] += add;
        __syncthreads();
    }
    if (t < SCAN_B) bsum[t] = buf[t] - v;
}

// add block offsets; produce rowptr + cursor
__global__ __launch_bounds__(256) void k_scanC(int* __restrict__ rowptr,
                                               int* __restrict__ cursor,
                                               const int* __restrict__ bsum) {
    int idx = blockIdx.x * 256 + threadIdx.x;
    if (idx <= NN) {
        int r = rowptr[idx] + bsum[blockIdx.x];
        rowptr[idx] = r;
        cursor[idx] = r;
    }
}

__global__ __launch_bounds__(256) void k_fill(const int* __restrict__ ei,
                                              int* __restrict__ cursor,
                                              int* __restrict__ perm) {
    int e = blockIdx.x * blockDim.x + threadIdx.x;
    if (e < EE) perm[e] = atomicAdd(&cursor[ei[EE + e]], 1);
}

// in-block BN finalize: stats -> scale/shift in LDS
__device__ __forceinline__ void bn_scsh(const float* __restrict__ stats,
                                        const float* __restrict__ gamma,
                                        const float* __restrict__ beta,
                                        int flag, float* sc, float* sh) {
    if (flag && threadIdx.x < 32) {
        int o = threadIdx.x;
        float mu = stats[o] * (1.0f / NN);
        float var = stats[32 + o] * (1.0f / NN) - mu * mu;
        float s = gamma[o] * rsqrtf(var + BN_EPS);
        sc[o] = s;
        sh[o] = fmaf(-mu, s, beta[o]);
    }
    __syncthreads();
}

// ---------------- per-layer kernels ----------------
// message per edge -> CSR-permuted slot; h read through fused BN+leakyrelu
__global__ __launch_bounds__(256) void k_msg(
    const float* __restrict__ h, const int* __restrict__ ei,
    const float* __restrict__ ea, const float* __restrict__ W1,
    const float* __restrict__ b1, const float* __restrict__ W2,
    const float* __restrict__ b2,
    const float* __restrict__ stats, const float* __restrict__ gamma,
    const float* __restrict__ beta, int flag,
    const int* __restrict__ perm, float* __restrict__ m)
{
    __shared__ float sc[32], sh[32];
    bn_scsh(stats, gamma, beta, flag, sc, sh);

    int e = blockIdx.x * blockDim.x + threadIdx.x;
    if (e >= EE) return;
    int s = ei[e];
    float2 a = ((const float2*)ea)[e];

    float ek[11];
#pragma unroll
    for (int k = 0; k < 10; ++k)
        ek[k] = fmaxf(fmaf(a.x, W1[k], fmaf(a.y, W1[10 + k], b1[k])), 0.0f);
    ek[10] = 1.0f;   // b2 as 11th basis matrix

    float hv[32];
    const float4* hp = (const float4*)(h + s * 32);
#pragma unroll
    for (int q = 0; q < 8; ++q) {
        float4 t = hp[q];
        hv[4 * q] = t.x; hv[4 * q + 1] = t.y; hv[4 * q + 2] = t.z; hv[4 * q + 3] = t.w;
    }
    if (flag) {
#pragma unroll
        for (int i = 0; i < 32; ++i) {
            float y = fmaf(hv[i], sc[i], sh[i]);
            hv[i] = y > 0.f ? y : SLOPE * y;
        }
    }

    float acc[32];
#pragma unroll
    for (int o = 0; o < 32; ++o) acc[o] = 0.0f;

    for (int k = 0; k < 11; ++k) {
        const float* w2k = (k < 10) ? (W2 + k * 1024) : b2;   // wave-uniform
        float ekk = ek[k];
#pragma unroll
        for (int i = 0; i < 32; ++i) {
            float z = ekk * hv[i];
#pragma unroll
            for (int o = 0; o < 32; ++o) acc[o] = fmaf(z, w2k[i * 32 + o], acc[o]);
        }
    }

    float4* mp = (float4*)(m + (size_t)perm[e] * 32);
#pragma unroll
    for (int q = 0; q < 8; ++q)
        mp[q] = make_float4(acc[4 * q], acc[4 * q + 1], acc[4 * q + 2], acc[4 * q + 3]);
}

// 8 threads/node: hpre[v] = bias + norm(h[v])@root + contiguous CSR message rows
__global__ __launch_bounds__(256) void k_agg(
    const float* __restrict__ h, const float* __restrict__ m,
    const int* __restrict__ rowptr,
    const float* __restrict__ root, const float* __restrict__ bias,
    const float* __restrict__ stats_prev, const float* __restrict__ gamma,
    const float* __restrict__ beta, int flag,
    float* __restrict__ hpre, float* __restrict__ stats_out)
{
    __shared__ float sc[32], sh[32];
    bn_scsh(stats_prev, gamma, beta, flag, sc, sh);

    int v = blockIdx.x * 32 + (threadIdx.x >> 3);
    int cg = threadIdx.x & 7;
    float4 acc = make_float4(0.f, 0.f, 0.f, 0.f);

    if (v < NN) {
        float hn[32];
        const float4* hp = (const float4*)(h + v * 32);
#pragma unroll
        for (int q = 0; q < 8; ++q) {
            float4 t = hp[q];
            hn[4 * q] = t.x; hn[4 * q + 1] = t.y; hn[4 * q + 2] = t.z; hn[4 * q + 3] = t.w;
        }
        if (flag) {
#pragma unroll
            for (int i = 0; i < 32; ++i) {
                float y = fmaf(hn[i], sc[i], sh[i]);
                hn[i] = y > 0.f ? y : SLOPE * y;
            }
        }
        acc = ((const float4*)bias)[cg];
#pragma unroll
        for (int i = 0; i < 32; ++i) {
            float4 r = ((const float4*)(root + i * 32))[cg];
            acc.x = fmaf(hn[i], r.x, acc.x);
            acc.y = fmaf(hn[i], r.y, acc.y);
            acc.z = fmaf(hn[i], r.z, acc.z);
            acc.w = fmaf(hn[i], r.w, acc.w);
        }
        int p0 = rowptr[v], p1 = rowptr[v + 1];
        for (int p = p0; p < p1; ++p) {
            float4 t = ((const float4*)(m + (size_t)p * 32))[cg];
            acc.x += t.x; acc.y += t.y; acc.z += t.z; acc.w += t.w;
        }
        ((float4*)(hpre + v * 32))[cg] = acc;
    }

    // BN stats: butterfly over 8 nodes/wave, LDS reduce over waves, 64 atomics/block
    float ss[8] = { acc.x, acc.y, acc.z, acc.w,
                    acc.x * acc.x, acc.y * acc.y, acc.z * acc.z, acc.w * acc.w };
#pragma unroll
    for (int d = 8; d < 64; d <<= 1) {
#pragma unroll
        for (int j = 0; j < 8; ++j) ss[j] += __shfl_xor(ss[j], d);
    }
    __shared__ float ls[2][4][8][4];
    int wave = threadIdx.x >> 6, lane = threadIdx.x & 63;
    if (lane < 8) {
#pragma unroll
        for (int j = 0; j < 4; ++j) {
            ls[0][wave][lane][j] = ss[j];
            ls[1][wave][lane][j] = ss[4 + j];
        }
    }
    __syncthreads();
    if (threadIdx.x < 64) {
        int stat = threadIdx.x >> 5, idx = threadIdx.x & 31;
        int cgg = idx >> 2, ch = idx & 3;
        float val = ls[stat][0][cgg][ch] + ls[stat][1][cgg][ch]
                  + ls[stat][2][cgg][ch] + ls[stat][3][cgg][ch];
        unsafeAtomicAdd(&stats_out[stat * 32 + idx], val);
    }
}

// final-layer norm fused
__global__ __launch_bounds__(256) void k_logits(const float* __restrict__ h,
                                                const float* __restrict__ fcW,
                                                const float* __restrict__ fcb,
                                                const float* __restrict__ stats,
                                                const float* __restrict__ gamma,
                                                const float* __restrict__ beta,
                                                float* __restrict__ out) {
    __shared__ float sc[32], sh[32];
    bn_scsh(stats, gamma, beta, 1, sc, sh);

    int v = blockIdx.x * blockDim.x + threadIdx.x;
    if (v >= NN) return;
    float hv[32];
    const float4* hp = (const float4*)(h + v * 32);
#pragma unroll
    for (int q = 0; q < 8; ++q) {
        float4 t = hp[q];
        hv[4 * q] = t.x; hv[4 * q + 1] = t.y; hv[4 * q + 2] = t.z; hv[4 * q + 3] = t.w;
    }
#pragma unroll
    for (int i = 0; i < 32; ++i) {
        float y = fmaf(hv[i], sc[i], sh[i]);
        hv[i] = y > 0.f ? y : SLOPE * y;
    }
    float lg[13];
#pragma unroll
    for (int c = 0; c < 13; ++c) lg[c] = fcb[c];
#pragma unroll
    for (int i = 0; i < 32; ++i) {
        float z = hv[i];
#pragma unroll
        for (int c = 0; c < 13; ++c) lg[c] = fmaf(z, fcW[i * 13 + c], lg[c]);
    }
    float mx = lg[0];
#pragma unroll
    for (int c = 1; c < 13; ++c) mx = fmaxf(mx, lg[c]);
    float sum = 0.0f;
#pragma unroll
    for (int c = 0; c < 13; ++c) sum += expf(lg[c] - mx);
    float lse = mx + logf(sum);
#pragma unroll
    for (int c = 0; c < 13; ++c) out[v * 13 + c] = lg[c] - lse;
}

// ---------------- launch ----------------
extern "C" void kernel_launch(void* const* d_in, const int* in_sizes, int n_in,
                              void* d_out, int out_size, void* d_ws, size_t ws_size,
                              hipStream_t stream) {
    const float* x     = (const float*)d_in[0];
    const int*   ei    = (const int*)  d_in[1];
    const float* ea    = (const float*)d_in[2];
    const float* netW1 = (const float*)d_in[3];
    const float* netb1 = (const float*)d_in[4];
    const float* netW2 = (const float*)d_in[5];
    const float* netb2 = (const float*)d_in[6];
    const float* root  = (const float*)d_in[7];
    const float* cbias = (const float*)d_in[8];
    const float* gamma = (const float*)d_in[9];
    const float* beta  = (const float*)d_in[10];
    const float* fcW   = (const float*)d_in[11];
    const float* fcb   = (const float*)d_in[12];
    float* out = (float*)d_out;

    char* w = (char*)d_ws;
    float* m      = (float*)(w);                 // 19,200,000 B
    float* hA     = (float*)(w + 19200000);      //  6,400,000 B
    float* hB     = (float*)(w + 25600000);      //  6,400,000 B
    int*   rowptr = (int*)  (w + 32000000);      //    200,064 B
    int*   cursor = (int*)  (w + 32200064);      //    200,064 B
    int*   perm   = (int*)  (w + 32400128);      //    600,000 B
    float* stats  = (float*)(w + 33000128);      //        768 B
    int*   bsum   = (int*)  (w + 33000896);      //      1,024 B
    int*   cnt    = (int*)w;                     // overlaps m (used only before m is written)

    hipMemsetAsync(cnt, 0, (NN + 1) * sizeof(int), stream);
    hipMemsetAsync(stats, 0, 768, stream);

    k_count<<<(EE + 255) / 256, 256, 0, stream>>>(ei, cnt);
    k_scanA<<<SCAN_B, 256, 0, stream>>>(cnt, rowptr, bsum);
    k_scanB<<<1, 256, 0, stream>>>(bsum);
    k_scanC<<<SCAN_B, 256, 0, stream>>>(rowptr, cursor, bsum);
    k_fill <<<(EE + 255) / 256, 256, 0, stream>>>(ei, cursor, perm);

    const float* hcur = x;
    float* bufs[2] = { hA, hB };
    for (int i = 0; i < 3; ++i) {
        float* hnext = bufs[i & 1];
        const float* stprev = stats + (i - 1) * 64;   // unused when i==0
        k_msg<<<(EE + 255) / 256, 256, 0, stream>>>(
            hcur, ei, ea, netW1 + i * 20, netb1 + i * 10,
            netW2 + i * 10240, netb2 + i * 1024,
            stprev, gamma + (i - 1) * 32, beta + (i - 1) * 32, i > 0, perm, m);
        k_agg<<<(NN + 31) / 32, 256, 0, stream>>>(
            hcur, m, rowptr, root + i * 1024, cbias + i * 32,
            stprev, gamma + (i - 1) * 32, beta + (i - 1) * 32, i > 0,
            hnext, stats + i * 64);
        hcur = hnext;
    }
    k_logits<<<(NN + 255) / 256, 256, 0, stream>>>(
        hcur, fcW, fcb, stats + 2 * 64, gamma + 2 * 32, beta + 2 * 32, out);
}

// Round 5
// 482.030 us; speedup vs baseline: 4.3656x; 1.0649x over previous
//
#include <hip/hip_runtime.h>

#define NN 50000
#define EE 150000
#define BN_EPS 1e-5f
#define SLOPE 0.01f
#define SCAN_B 196   // ceil((NN+1)/256)

// ---------------- CSR build ----------------
__global__ __launch_bounds__(256) void k_count(const int* __restrict__ ei, int* __restrict__ cnt) {
    int e = blockIdx.x * blockDim.x + threadIdx.x;
    if (e < EE) atomicAdd(&cnt[ei[EE + e]], 1);
}

__global__ __launch_bounds__(256) void k_scanA(const int* __restrict__ cnt,
                                               int* __restrict__ rowptr,
                                               int* __restrict__ bsum) {
    __shared__ int buf[256];
    int t = threadIdx.x;
    int idx = blockIdx.x * 256 + t;
    int v = (idx <= NN) ? cnt[idx] : 0;
    buf[t] = v;
    __syncthreads();
    for (int off = 1; off < 256; off <<= 1) {
        int add = (t >= off) ? buf[t - off] : 0;
        __syncthreads();
        buf[t] += add;
        __syncthreads();
    }
    if (idx <= NN) rowptr[idx] = buf[t] - v;
    if (t == 255) bsum[blockIdx.x] = buf[255];
}

__global__ __launch_bounds__(256) void k_scanB(int* __restrict__ bsum) {
    __shared__ int buf[256];
    int t = threadIdx.x;
    int v = (t < SCAN_B) ? bsum[t] : 0;
    buf[t] = v;
    __syncthreads();
    for (int off = 1; off < 256; off <<= 1) {
        int add = (t >= off) ? buf[t - off] : 0;
        __syncthreads();
        buf[t] += add;
        __syncthreads();
    }
    if (t < SCAN_B) bsum[t] = buf[t] - v;
}

__global__ __launch_bounds__(256) void k_scanC(int* __restrict__ rowptr,
                                               int* __restrict__ cursor,
                                               const int* __restrict__ bsum) {
    int idx = blockIdx.x * 256 + threadIdx.x;
    if (idx <= NN) {
        int r = rowptr[idx] + bsum[blockIdx.x];
        rowptr[idx] = r;
        cursor[idx] = r;
    }
}

__global__ __launch_bounds__(256) void k_fill(const int* __restrict__ ei,
                                              int* __restrict__ cursor,
                                              int* __restrict__ perm) {
    int e = blockIdx.x * blockDim.x + threadIdx.x;
    if (e < EE) perm[e] = atomicAdd(&cursor[ei[EE + e]], 1);
}

// in-block BN finalize: stats -> scale/shift in LDS (no trailing sync; caller syncs)
__device__ __forceinline__ void bn_scsh(const float* __restrict__ stats,
                                        const float* __restrict__ gamma,
                                        const float* __restrict__ beta,
                                        int flag, float* sc, float* sh) {
    if (flag && threadIdx.x < 32) {
        int o = threadIdx.x;
        float mu = stats[o] * (1.0f / NN);
        float var = stats[32 + o] * (1.0f / NN) - mu * mu;
        float s = gamma[o] * rsqrtf(var + BN_EPS);
        sc[o] = s;
        sh[o] = fmaf(-mu, s, beta[o]);
    }
}

// ---------------- per-layer kernels ----------------
// message per edge -> CSR-permuted slot; weights LDS-staged; h through fused BN+leakyrelu
__global__ __launch_bounds__(256) void k_msg(
    const float* __restrict__ h, const int* __restrict__ ei,
    const float* __restrict__ ea, const float* __restrict__ W1,
    const float* __restrict__ b1, const float* __restrict__ W2,
    const float* __restrict__ b2,
    const float* __restrict__ stats, const float* __restrict__ gamma,
    const float* __restrict__ beta, int flag,
    const int* __restrict__ perm, float* __restrict__ m)
{
    __shared__ float4 sw[2816];          // 11 x 1024 floats: W2[0..9], b2 as #10 (45 KB)
    __shared__ float sc[32], sh[32];

    int t = threadIdx.x;
    const float4* W2v = (const float4*)W2;
#pragma unroll
    for (int j = 0; j < 10; ++j) sw[j * 256 + t] = W2v[j * 256 + t];
    sw[2560 + t] = ((const float4*)b2)[t];
    bn_scsh(stats, gamma, beta, flag, sc, sh);
    __syncthreads();

    int e = blockIdx.x * blockDim.x + t;
    if (e >= EE) return;
    int s = ei[e];
    float2 a = ((const float2*)ea)[e];

    float ek[11];
#pragma unroll
    for (int k = 0; k < 10; ++k)
        ek[k] = fmaxf(fmaf(a.x, W1[k], fmaf(a.y, W1[10 + k], b1[k])), 0.0f);
    ek[10] = 1.0f;

    float hv[32];
    const float4* hp = (const float4*)(h + s * 32);
#pragma unroll
    for (int q = 0; q < 8; ++q) {
        float4 tt = hp[q];
        hv[4 * q] = tt.x; hv[4 * q + 1] = tt.y; hv[4 * q + 2] = tt.z; hv[4 * q + 3] = tt.w;
    }
    if (flag) {
#pragma unroll
        for (int i = 0; i < 32; ++i) {
            float y = fmaf(hv[i], sc[i], sh[i]);
            hv[i] = y > 0.f ? y : SLOPE * y;
        }
    }

    float4 acc[8];
#pragma unroll
    for (int o = 0; o < 8; ++o) acc[o] = make_float4(0.f, 0.f, 0.f, 0.f);

    for (int k = 0; k < 11; ++k) {           // rolled: keeps body ~10 KB (I$-safe)
        float ekk = ek[k];
        const float4* wk = &sw[k * 256];
#pragma unroll
        for (int i = 0; i < 32; ++i) {
            float z = ekk * hv[i];
            const float4* wr = wk + i * 8;
#pragma unroll
            for (int o = 0; o < 8; ++o) {
                float4 wv = wr[o];           // wave-uniform ds_read_b128 broadcast
                acc[o].x = fmaf(z, wv.x, acc[o].x);
                acc[o].y = fmaf(z, wv.y, acc[o].y);
                acc[o].z = fmaf(z, wv.z, acc[o].z);
                acc[o].w = fmaf(z, wv.w, acc[o].w);
            }
        }
    }

    float4* mp = (float4*)(m + (size_t)perm[e] * 32);
#pragma unroll
    for (int o = 0; o < 8; ++o) mp[o] = acc[o];
}

// 8 threads/node: hpre[v] = bias + norm(h[v])@root + contiguous CSR message rows
__global__ __launch_bounds__(256) void k_agg(
    const float* __restrict__ h, const float* __restrict__ m,
    const int* __restrict__ rowptr,
    const float* __restrict__ root, const float* __restrict__ bias,
    const float* __restrict__ stats_prev, const float* __restrict__ gamma,
    const float* __restrict__ beta, int flag,
    float* __restrict__ hpre, float* __restrict__ stats_out)
{
    __shared__ float sc[32], sh[32];
    bn_scsh(stats_prev, gamma, beta, flag, sc, sh);
    __syncthreads();

    int v = blockIdx.x * 32 + (threadIdx.x >> 3);
    int cg = threadIdx.x & 7;
    float4 acc = make_float4(0.f, 0.f, 0.f, 0.f);

    if (v < NN) {
        float hn[32];
        const float4* hp = (const float4*)(h + v * 32);
#pragma unroll
        for (int q = 0; q < 8; ++q) {
            float4 t = hp[q];
            hn[4 * q] = t.x; hn[4 * q + 1] = t.y; hn[4 * q + 2] = t.z; hn[4 * q + 3] = t.w;
        }
        if (flag) {
#pragma unroll
            for (int i = 0; i < 32; ++i) {
                float y = fmaf(hn[i], sc[i], sh[i]);
                hn[i] = y > 0.f ? y : SLOPE * y;
            }
        }
        acc = ((const float4*)bias)[cg];
#pragma unroll
        for (int i = 0; i < 32; ++i) {
            float4 r = ((const float4*)(root + i * 32))[cg];
            acc.x = fmaf(hn[i], r.x, acc.x);
            acc.y = fmaf(hn[i], r.y, acc.y);
            acc.z = fmaf(hn[i], r.z, acc.z);
            acc.w = fmaf(hn[i], r.w, acc.w);
        }
        int p0 = rowptr[v], p1 = rowptr[v + 1];
        for (int p = p0; p < p1; ++p) {
            float4 t = ((const float4*)(m + (size_t)p * 32))[cg];
            acc.x += t.x; acc.y += t.y; acc.z += t.z; acc.w += t.w;
        }
        ((float4*)(hpre + v * 32))[cg] = acc;
    }

    // BN stats: butterfly over 8 nodes/wave, LDS reduce over waves, 64 atomics/block
    float ss[8] = { acc.x, acc.y, acc.z, acc.w,
                    acc.x * acc.x, acc.y * acc.y, acc.z * acc.z, acc.w * acc.w };
#pragma unroll
    for (int d = 8; d < 64; d <<= 1) {
#pragma unroll
        for (int j = 0; j < 8; ++j) ss[j] += __shfl_xor(ss[j], d);
    }
    __shared__ float ls[2][4][8][4];
    int wave = threadIdx.x >> 6, lane = threadIdx.x & 63;
    if (lane < 8) {
#pragma unroll
        for (int j = 0; j < 4; ++j) {
            ls[0][wave][lane][j] = ss[j];
            ls[1][wave][lane][j] = ss[4 + j];
        }
    }
    __syncthreads();
    if (threadIdx.x < 64) {
        int stat = threadIdx.x >> 5, idx = threadIdx.x & 31;
        int cgg = idx >> 2, ch = idx & 3;
        float val = ls[stat][0][cgg][ch] + ls[stat][1][cgg][ch]
                  + ls[stat][2][cgg][ch] + ls[stat][3][cgg][ch];
        unsafeAtomicAdd(&stats_out[stat * 32 + idx], val);
    }
}

// final-layer norm fused
__global__ __launch_bounds__(256) void k_logits(const float* __restrict__ h,
                                                const float* __restrict__ fcW,
                                                const float* __restrict__ fcb,
                                                const float* __restrict__ stats,
                                                const float* __restrict__ gamma,
                                                const float* __restrict__ beta,
                                                float* __restrict__ out) {
    __shared__ float sc[32], sh[32];
    bn_scsh(stats, gamma, beta, 1, sc, sh);
    __syncthreads();

    int v = blockIdx.x * blockDim.x + threadIdx.x;
    if (v >= NN) return;
    float hv[32];
    const float4* hp = (const float4*)(h + v * 32);
#pragma unroll
    for (int q = 0; q < 8; ++q) {
        float4 t = hp[q];
        hv[4 * q] = t.x; hv[4 * q + 1] = t.y; hv[4 * q + 2] = t.z; hv[4 * q + 3] = t.w;
    }
#pragma unroll
    for (int i = 0; i < 32; ++i) {
        float y = fmaf(hv[i], sc[i], sh[i]);
        hv[i] = y > 0.f ? y : SLOPE * y;
    }
    float lg[13];
#pragma unroll
    for (int c = 0; c < 13; ++c) lg[c] = fcb[c];
#pragma unroll
    for (int i = 0; i < 32; ++i) {
        float z = hv[i];
#pragma unroll
        for (int c = 0; c < 13; ++c) lg[c] = fmaf(z, fcW[i * 13 + c], lg[c]);
    }
    float mx = lg[0];
#pragma unroll
    for (int c = 1; c < 13; ++c) mx = fmaxf(mx, lg[c]);
    float sum = 0.0f;
#pragma unroll
    for (int c = 0; c < 13; ++c) sum += expf(lg[c] - mx);
    float lse = mx + logf(sum);
#pragma unroll
    for (int c = 0; c < 13; ++c) out[v * 13 + c] = lg[c] - lse;
}

// ---------------- launch ----------------
extern "C" void kernel_launch(void* const* d_in, const int* in_sizes, int n_in,
                              void* d_out, int out_size, void* d_ws, size_t ws_size,
                              hipStream_t stream) {
    const float* x     = (const float*)d_in[0];
    const int*   ei    = (const int*)  d_in[1];
    const float* ea    = (const float*)d_in[2];
    const float* netW1 = (const float*)d_in[3];
    const float* netb1 = (const float*)d_in[4];
    const float* netW2 = (const float*)d_in[5];
    const float* netb2 = (const float*)d_in[6];
    const float* root  = (const float*)d_in[7];
    const float* cbias = (const float*)d_in[8];
    const float* gamma = (const float*)d_in[9];
    const float* beta  = (const float*)d_in[10];
    const float* fcW   = (const float*)d_in[11];
    const float* fcb   = (const float*)d_in[12];
    float* out = (float*)d_out;

    char* w = (char*)d_ws;
    float* m      = (float*)(w);                 // 19,200,000 B
    float* hA     = (float*)(w + 19200000);      //  6,400,000 B
    float* hB     = (float*)(w + 25600000);      //  6,400,000 B
    int*   rowptr = (int*)  (w + 32000000);      //    200,064 B
    int*   cursor = (int*)  (w + 32200064);      //    200,064 B
    int*   perm   = (int*)  (w + 32400128);      //    600,000 B
    float* stats  = (float*)(w + 33000128);      //        768 B
    int*   bsum   = (int*)  (w + 33000896);      //      1,024 B
    int*   cnt    = (int*)w;                     // overlaps m (used only before m is written)

    hipMemsetAsync(cnt, 0, (NN + 1) * sizeof(int), stream);
    hipMemsetAsync(stats, 0, 768, stream);

    k_count<<<(EE + 255) / 256, 256, 0, stream>>>(ei, cnt);
    k_scanA<<<SCAN_B, 256, 0, stream>>>(cnt, rowptr, bsum);
    k_scanB<<<1, 256, 0, stream>>>(bsum);
    k_scanC<<<SCAN_B, 256, 0, stream>>>(rowptr, cursor, bsum);
    k_fill <<<(EE + 255) / 256, 256, 0, stream>>>(ei, cursor, perm);

    const float* hcur = x;
    float* bufs[2] = { hA, hB };
    for (int i = 0; i < 3; ++i) {
        float* hnext = bufs[i & 1];
        const float* stprev = stats + (i - 1) * 64;   // unused when i==0
        k_msg<<<(EE + 255) / 256, 256, 0, stream>>>(
            hcur, ei, ea, netW1 + i * 20, netb1 + i * 10,
            netW2 + i * 10240, netb2 + i * 1024,
            stprev, gamma + (i - 1) * 32, beta + (i - 1) * 32, i > 0, perm, m);
        k_agg<<<(NN + 31) / 32, 256, 0, stream>>>(
            hcur, m, rowptr, root + i * 1024, cbias + i * 32,
            stprev, gamma + (i - 1) * 32, beta + (i - 1) * 32, i > 0,
            hnext, stats + i * 64);
        hcur = hnext;
    }
    k_logits<<<(NN + 255) / 256, 256, 0, stream>>>(
        hcur, fcW, fcb, stats + 2 * 64, gamma + 2 * 32, beta + 2 * 32, out);
}